// Round 2
// baseline (222.052 us; speedup 1.0000x reference)
//
#include <hip/hip_runtime.h>
#include <hip/hip_bf16.h>

// Problem constants
#define BB 4
#define CC 512
#define TT 2048
static constexpr long CT  = (long)CC * TT;   // 1048576 = 2^20
static constexpr long TC  = (long)TT * CC;
static constexpr long TTT = (long)TT * TT;   // 4194304
static constexpr float SM_SCALE = 0.04419417382415922f; // 1/sqrt(512)

typedef __bf16 bf16;
typedef __attribute__((ext_vector_type(8))) __bf16 bf16x8;
typedef __attribute__((ext_vector_type(4))) __bf16 bf16x4;
typedef __attribute__((ext_vector_type(4))) float f32x4;

// Async global->LDS, 16B per lane. LDS dest must be wave-uniform base + lane*16.
__device__ __forceinline__ void load_lds16(const bf16* g, bf16* l)
{
    __builtin_amdgcn_global_load_lds(
        (const __attribute__((address_space(1))) void*)g,
        (__attribute__((address_space(3))) void*)l, 16, 0, 0);
}

// ---------------------------------------------------------------------------
// Shared NT-GEMM core: acc[m][n] += sum_k A[m][k]*B[n][k] (k-contig, ld==K).
// XOR-swizzled LDS at 16B-chunk granularity (bank-conflict-free ds_read_b128).
// ---------------------------------------------------------------------------
template <int TM, int TN, int WR, int WC, int BK>
struct Core {
    static constexpr int THREADS = WR * WC * 64;
    static constexpr int MI = TM / (WR * 16);
    static constexpr int NI = TN / (WC * 16);
    static constexpr int CPR = BK / 8;
    static constexpr int RSH = (BK == 64) ? 3 : 2;
    static constexpr int CMASK = CPR - 1;
    static constexpr int CHUNKS = (TM + TN) * CPR;
    static constexpr int ACH = TM * CPR;
    static constexpr int CPT = CHUNKS / THREADS;
    static_assert(CPT * THREADS == CHUNKS, "chunk divisibility");

    __device__ static __forceinline__ void run(
        const bf16* __restrict__ Ab, const bf16* __restrict__ Bb,
        int K, int m0, int n0, bf16* As, bf16* Bs, f32x4 (&acc)[MI][NI])
    {
        const int tid  = threadIdx.x;
        const int lane = tid & 63;
        const int wid  = tid >> 6;
        const int wr = (wid / WC) * (MI * 16);
        const int wc = (wid % WC) * (NI * 16);
        const int lm = lane & 15;
        const int lq = lane >> 4;
        for (int k0 = 0; k0 < K; k0 += BK) {
#pragma unroll
            for (int i = 0; i < CPT; ++i) {
                int c = tid + i * THREADS;
                if (c < ACH) {
                    int row = c >> RSH;
                    int gc  = (c & CMASK) ^ (row & CMASK);
                    load_lds16(Ab + (long)(m0 + row) * K + k0 + gc * 8, As + c * 8);
                } else {
                    int d = c - ACH;
                    int row = d >> RSH;
                    int gc  = (d & CMASK) ^ (row & CMASK);
                    load_lds16(Bb + (long)(n0 + row) * K + k0 + gc * 8, Bs + d * 8);
                }
            }
            __syncthreads();
#pragma unroll
            for (int ks = 0; ks < BK / 32; ++ks) {
                bf16x8 af[MI], bfr[NI];
#pragma unroll
                for (int i = 0; i < MI; ++i) {
                    int ar = wr + i * 16 + lm;
                    int cc = (ks * 4 + lq) ^ (ar & CMASK);
                    af[i] = *(const bf16x8*)(As + ar * BK + cc * 8);
                }
#pragma unroll
                for (int i = 0; i < NI; ++i) {
                    int br = wc + i * 16 + lm;
                    int cc = (ks * 4 + lq) ^ (br & CMASK);
                    bfr[i] = *(const bf16x8*)(Bs + br * BK + cc * 8);
                }
#pragma unroll
                for (int mi = 0; mi < MI; ++mi)
#pragma unroll
                    for (int ni = 0; ni < NI; ++ni)
                        acc[mi][ni] = __builtin_amdgcn_mfma_f32_16x16x32_bf16(
                            af[mi], bfr[ni], acc[mi][ni], 0, 0, 0);
            }
            __syncthreads();
        }
    }
};

using CO = Core<128, 128, 4, 2, 64>;   // 8-wave 128x128 workhorse

// ---------------------------------------------------------------------------
// QV core: like Core<128,128,4,2,64> but the 128-row B tile is staged from TWO
// pointers: rows 0..63 from Bq (Wq slab), rows 64..127 from Bv (Wv slab).
// One shared A (featT) staging feeds both Q and V GEMMs.
// ---------------------------------------------------------------------------
struct CoreQV {
    static constexpr int THREADS = 512;
    static constexpr int MI = 2;
    static constexpr int NI = 4;
    static constexpr int BK = 64;
    static constexpr int CPR = 8, RSH = 3, CMASK = 7;
    static constexpr int ACH = 128 * 8;          // A chunks
    static constexpr int CHUNKS = 256 * 8;       // A + B
    static constexpr int CPT = CHUNKS / THREADS; // 4

    __device__ static __forceinline__ void run(
        const bf16* __restrict__ Ab, const bf16* __restrict__ Bq,
        const bf16* __restrict__ Bv,
        int m0, bf16* As, bf16* Bs, f32x4 (&acc)[MI][NI])
    {
        const int tid  = threadIdx.x;
        const int lane = tid & 63;
        const int wid  = tid >> 6;
        const int wr = (wid / 2) * 32;
        const int wc = (wid % 2) * 64;
        const int lm = lane & 15;
        const int lq = lane >> 4;
        for (int k0 = 0; k0 < 512; k0 += BK) {
#pragma unroll
            for (int i = 0; i < CPT; ++i) {
                int c = tid + i * THREADS;
                if (c < ACH) {
                    int row = c >> RSH;
                    int gc  = (c & CMASK) ^ (row & CMASK);
                    load_lds16(Ab + (long)(m0 + row) * 512 + k0 + gc * 8, As + c * 8);
                } else {
                    int d = c - ACH;
                    int row = d >> RSH;
                    int gc  = (d & CMASK) ^ (row & CMASK);
                    const bf16* src = (row < 64)
                        ? Bq + (long)row * 512
                        : Bv + (long)(row - 64) * 512;
                    load_lds16(src + k0 + gc * 8, Bs + d * 8);
                }
            }
            __syncthreads();
#pragma unroll
            for (int ks = 0; ks < 2; ++ks) {
                bf16x8 af[MI], bfr[NI];
#pragma unroll
                for (int i = 0; i < MI; ++i) {
                    int ar = wr + i * 16 + lm;
                    int cc = (ks * 4 + lq) ^ (ar & CMASK);
                    af[i] = *(const bf16x8*)(As + ar * BK + cc * 8);
                }
#pragma unroll
                for (int i = 0; i < NI; ++i) {
                    int br = wc + i * 16 + lm;
                    int cc = (ks * 4 + lq) ^ (br & CMASK);
                    bfr[i] = *(const bf16x8*)(Bs + br * BK + cc * 8);
                }
#pragma unroll
                for (int mi = 0; mi < MI; ++mi)
#pragma unroll
                    for (int ni = 0; ni < NI; ++ni)
                        acc[mi][ni] = __builtin_amdgcn_mfma_f32_16x16x32_bf16(
                            af[mi], bfr[ni], acc[mi][ni], 0, 0, 0);
            }
            __syncthreads();
        }
    }
};

// ---------------------------------------------------------------------------
// Q+V with ONE shared featT staging. Even waves (wc=0) hold the Q half; odd
// waves (wc=64) the V half. V is stored in NATURAL layout Vn[b][s][c] now
// (consumed as the B-side of gemm_vs), and the V half also accumulates
// vl[b][s] = V[s]·Wl (f32 atomics) for the u = P·vl identity.
// ---------------------------------------------------------------------------
__global__ __launch_bounds__(512)
void gemm_qv_kernel(const bf16* __restrict__ featT, const bf16* __restrict__ Wq_bf,
                    const bf16* __restrict__ Wv_bf, bf16* __restrict__ Qb,
                    bf16* __restrict__ Vn, const float* __restrict__ bq,
                    const float* __restrict__ bv, const float* __restrict__ wkc,
                    const float* __restrict__ bk, float* __restrict__ qb,
                    const float* __restrict__ Wl, float* __restrict__ vl)
{
    __shared__ bf16 As[128 * 64];
    __shared__ bf16 Bs[128 * 64];
    const int rb = blockIdx.z;
    const int m0 = blockIdx.y * 128;
    const int ng = blockIdx.x;               // channel group [ng*64, ng*64+64)
    const long wofs = (long)(ng * 64) * 512;
    f32x4 acc[2][4] = {};
    CoreQV::run(featT + (long)rb * TC, Wq_bf + wofs, Wv_bf + wofs, m0, As, Bs, acc);

    const int lane = threadIdx.x & 63, wid = threadIdx.x >> 6;
    const int wr = (wid / 2) * 32;
    const bool isV = wid & 1;
    const int lm = lane & 15, lq = lane >> 4;

    if (isV) {
        bf16* outV = Vn + (long)rb * TC;
        float* vlb = vl + (long)rb * TT;
        float vs_[2][4] = {};
#pragma unroll
        for (int mi = 0; mi < 2; ++mi)
#pragma unroll
            for (int ni = 0; ni < 4; ++ni) {
                int n = ng * 64 + ni * 16 + lm;
                float bn = bv[n], wn = Wl[n];
#pragma unroll
                for (int r = 0; r < 4; ++r) {
                    int m = m0 + wr + mi * 16 + lq * 4 + r;
                    float v = acc[mi][ni][r] + bn;
                    outV[(long)m * 512 + n] = (bf16)v;
                    vs_[mi][r] += v * wn;
                }
            }
#pragma unroll
        for (int mi = 0; mi < 2; ++mi)
#pragma unroll
            for (int r = 0; r < 4; ++r) {
                float s = vs_[mi][r];
                s += __shfl_xor(s, 1, 64); s += __shfl_xor(s, 2, 64);
                s += __shfl_xor(s, 4, 64); s += __shfl_xor(s, 8, 64);
                if (lm == 0)
                    atomicAdd(vlb + m0 + wr + mi * 16 + lq * 4 + r, s);
            }
    } else {
        bf16* out = Qb + (long)rb * TC;
        float* qbb = qb + (long)rb * TT;
        float rs[2][4] = {};
#pragma unroll
        for (int mi = 0; mi < 2; ++mi)
#pragma unroll
            for (int ni = 0; ni < 4; ++ni) {
                int n = ng * 64 + ni * 16 + lm;
                float bn = bq[n], wn = wkc[n], kn = bk[n];
#pragma unroll
                for (int r = 0; r < 4; ++r) {
                    int m = m0 + wr + mi * 16 + lq * 4 + r;
                    float v = acc[mi][ni][r] + bn;
                    rs[mi][r] += v * kn;
                    out[(long)m * 512 + n] = (bf16)(v * wn);
                }
            }
#pragma unroll
        for (int mi = 0; mi < 2; ++mi)
#pragma unroll
            for (int r = 0; r < 4; ++r) {
                float s = rs[mi][r];
                s += __shfl_xor(s, 1, 64); s += __shfl_xor(s, 2, 64);
                s += __shfl_xor(s, 4, 64); s += __shfl_xor(s, 8, 64);
                if (lm == 0)
                    atomicAdd(qbb + m0 + wr + mi * 16 + lq * 4 + r, s);
            }
    }
}

// ---------------------------------------------------------------------------
// P = exp((Q'.featT^T + qb) * SM_SCALE) (UNNORMALIZED) + rsum atomics +
// u_raw atomics (u_raw[t] = sum_s P[t][s]*vl[s]; y·Wl = u_raw/rsum).
// 256x256 tile, 8 waves, 128 KiB double-buffered LDS, 8-phase schedule with
// counted vmcnt(4) (T3+T4) + setprio around MFMA clusters (T5).
// ---------------------------------------------------------------------------
__global__ __launch_bounds__(512, 2)
void gemm_s256_kernel(const bf16* __restrict__ Qb, const bf16* __restrict__ featT,
                      bf16* __restrict__ S, const float* __restrict__ qb,
                      float* __restrict__ rsum, const float* __restrict__ vl,
                      float* __restrict__ u)
{
    // [kbuf parity][op A=0/B=1][256 rows * 64 k], 128 KiB total
    __shared__ __align__(16) bf16 lds[2][2][256 * 64];
    const int id   = blockIdx.x;
    const int xcd  = id & 7, sIdx = id >> 3;         // sIdx in [0,32)
    const int bz   = xcd >> 1;
    const int n0   = (sIdx & 7) * 256;               // 8 n-tiles
    const int m0   = (((xcd & 1) << 2) + (sIdx >> 3)) * 256; // 4 m-tiles/half
    const bf16* __restrict__ Ab = Qb + (long)bz * TC;
    const bf16* __restrict__ Bb = featT + (long)bz * TC;

    const int tid  = threadIdx.x;
    const int lane = tid & 63;
    const int wid  = tid >> 6;
    const int lm = lane & 15, lq = lane >> 4;
    const int wrb = (wid >> 2) * 64;   // wave row sub-base within each 128-half
    const int wcb = (wid & 3) * 32;    // wave col sub-base within each 128-half

    f32x4 acc[8][4] = {};

#define FENCE asm volatile("" ::: "memory")

#define STAGE_HT(t, op, h)                                                    \
    do {                                                                      \
        const bf16* gp_ = (op) ? Bb : Ab;                                     \
        const int  br_  = ((op) ? n0 : m0) + (h) * 128;                       \
        bf16* lp_ = &lds[(t) & 1][op][(h) * 128 * 64];                        \
        _Pragma("unroll")                                                     \
        for (int i_ = 0; i_ < 2; ++i_) {                                      \
            int c_ = tid + i_ * 512;                                          \
            int r_ = c_ >> 3;                                                 \
            int g_ = (c_ & 7) ^ (r_ & 7);                                     \
            load_lds16(gp_ + (long)(br_ + r_) * 512 + (t) * 64 + g_ * 8,      \
                       lp_ + c_ * 8);                                         \
        }                                                                     \
    } while (0)

#define PHASE(t, qm, qn, doSt, st, sop, sh, doVm)                             \
    do {                                                                      \
        bf16x8 af[2][4], bfr[2][2];                                           \
        const bf16* Al_ = lds[(t) & 1][0];                                    \
        const bf16* Bl_ = lds[(t) & 1][1];                                    \
        _Pragma("unroll")                                                     \
        for (int ks = 0; ks < 2; ++ks) {                                      \
            _Pragma("unroll")                                                 \
            for (int j = 0; j < 4; ++j) {                                     \
                int ar = (qm) * 128 + wrb + j * 16 + lm;                      \
                int cc = (ks * 4 + lq) ^ (ar & 7);                            \
                af[ks][j] = *(const bf16x8*)(Al_ + ar * 64 + cc * 8);         \
            }                                                                 \
            _Pragma("unroll")                                                 \
            for (int j = 0; j < 2; ++j) {                                     \
                int br = (qn) * 128 + wcb + j * 16 + lm;                      \
                int cc = (ks * 4 + lq) ^ (br & 7);                            \
                bfr[ks][j] = *(const bf16x8*)(Bl_ + br * 64 + cc * 8);        \
            }                                                                 \
        }                                                                     \
        if (doSt) STAGE_HT(st, sop, sh);                                      \
        if (doVm) {                                                           \
            if ((t) < 6) asm volatile("s_waitcnt vmcnt(4)" ::: "memory");     \
            else         asm volatile("s_waitcnt vmcnt(0)" ::: "memory");     \
        }                                                                     \
        FENCE; __builtin_amdgcn_s_barrier(); FENCE;                           \
        __builtin_amdgcn_s_setprio(1);                                        \
        _Pragma("unroll")                                                     \
        for (int ks = 0; ks < 2; ++ks)                                        \
            _Pragma("unroll")                                                 \
            for (int j = 0; j < 4; ++j)                                       \
                _Pragma("unroll")                                             \
                for (int j2 = 0; j2 < 2; ++j2)                                \
                    acc[(qm) * 4 + j][(qn) * 2 + j2] =                        \
                        __builtin_amdgcn_mfma_f32_16x16x32_bf16(              \
                            af[ks][j], bfr[ks][j2],                           \
                            acc[(qm) * 4 + j][(qn) * 2 + j2], 0, 0, 0);       \
        __builtin_amdgcn_s_setprio(0);                                        \
        FENCE; __builtin_amdgcn_s_barrier(); FENCE;                           \
    } while (0)

    STAGE_HT(0, 0, 0); STAGE_HT(0, 1, 0); STAGE_HT(0, 0, 1); STAGE_HT(0, 1, 1);
    STAGE_HT(1, 0, 0); STAGE_HT(1, 1, 0);
    asm volatile("s_waitcnt vmcnt(4)" ::: "memory");
    FENCE; __builtin_amdgcn_s_barrier(); FENCE;

    for (int t = 0; t < 8; ++t) {
        PHASE(t, 0, 0, t + 1 < 8, t + 1, 0, 1, false); // stage A-hi(t+1)
        PHASE(t, 0, 1, t + 1 < 8, t + 1, 1, 1, false); // stage B-hi(t+1)
        PHASE(t, 1, 0, t + 2 < 8, t + 2, 0, 0, false); // stage A-lo(t+2)
        PHASE(t, 1, 1, t + 2 < 8, t + 2, 1, 0, true);  // stage B-lo(t+2)+vmcnt
    }
#undef PHASE
#undef STAGE_HT
#undef FENCE

    // Epilogue: exp, bf16 store, rsum + u_raw row atomics.
    bf16* outp = S + (long)bz * TTT;
    const float* qbb = qb + (long)bz * TT;
    const float* vlb = vl + (long)bz * TT;
    float* rsb = rsum + (long)bz * TT;
    float* ub  = u + (long)bz * TT;
#pragma unroll
    for (int mi = 0; mi < 8; ++mi) {
        const int mrow = m0 + (mi >> 2) * 128 + wrb + (mi & 3) * 16 + lq * 4;
        const f32x4 qv = *(const f32x4*)(qbb + mrow);
        float rp[4] = {0.f, 0.f, 0.f, 0.f};
        float up[4] = {0.f, 0.f, 0.f, 0.f};
#pragma unroll
        for (int ni = 0; ni < 4; ++ni) {
            const int ncol = n0 + (ni >> 1) * 128 + wcb + (ni & 1) * 16 + lm;
            const float vlv = vlb[ncol];
#pragma unroll
            for (int r = 0; r < 4; ++r) {
                float p = __expf((acc[mi][ni][r] + qv[r]) * SM_SCALE);
                outp[(long)(mrow + r) * 2048 + ncol] = (bf16)p;
                rp[r] += p;
                up[r] += p * vlv;
            }
        }
#pragma unroll
        for (int r = 0; r < 4; ++r) {
            float s2 = rp[r], s3 = up[r];
            s2 += __shfl_xor(s2, 1, 64); s2 += __shfl_xor(s2, 2, 64);
            s2 += __shfl_xor(s2, 4, 64); s2 += __shfl_xor(s2, 8, 64);
            s3 += __shfl_xor(s3, 1, 64); s3 += __shfl_xor(s3, 2, 64);
            s3 += __shfl_xor(s3, 4, 64); s3 += __shfl_xor(s3, 8, 64);
            if (lm == 0) {
                atomicAdd(rsb + mrow + r, s2);
                atomicAdd(ub + mrow + r, s3);
            }
        }
    }
}

// ---------------------------------------------------------------------------
// V't[b][c'][s] = sum_c Ws[c'][c] * Vn[b][s][c]   (NT: A=Ws rows, B=Vn rows).
// 256 blocks; per batch 4 m-tiles (c') x 16 n-tiles (s).
// ---------------------------------------------------------------------------
__global__ __launch_bounds__(512)
void gemm_vs_kernel(const bf16* __restrict__ Vn, const bf16* __restrict__ Ws_bf,
                    bf16* __restrict__ Vpt)
{
    __shared__ bf16 As[128 * 64];
    __shared__ bf16 Bs[128 * 64];
    const int id = blockIdx.x;
    const int xcd = id & 7, s = id >> 3;             // s in [0,32)
    const int bz = xcd >> 1;
    const int m0 = (((xcd & 1) << 1) + (s >> 4)) * 128;  // 4 c'-tiles
    const int n0 = (s & 15) * 128;                       // 16 s-tiles
    f32x4 acc[2][4] = {};
    CO::run(Ws_bf, Vn + (long)bz * TC, 512, m0, n0, As, Bs, acc);

    const int lane = threadIdx.x & 63, wid = threadIdx.x >> 6;
    const int wr = (wid / 2) * 32, wc = (wid % 2) * 64;
    const int lm = lane & 15, lq = lane >> 4;
    bf16* out = Vpt + (long)bz * CT;
#pragma unroll
    for (int mi = 0; mi < 2; ++mi)
#pragma unroll
        for (int ni = 0; ni < 4; ++ni) {
            int n = n0 + wc + ni * 16 + lm;
#pragma unroll
            for (int r = 0; r < 4; ++r) {
                int m = m0 + wr + mi * 16 + lq * 4 + r;
                out[(long)m * 2048 + n] = (bf16)acc[mi][ni][r];
            }
        }
}

// ---------------------------------------------------------------------------
// out[b][c'][t] = feat + (P·V't)/rsum[t] + bs[c'] + LN stats.
// Replaces gemm_y + gemm_final: A = S rows (k=s, K=2048), B = V't rows.
// 256 blocks; XCD ownership (bz=xcd>>1, t-half=xcd&1) matches gemm_s256's S
// writes, and n-tiles = 4 (vs 8 before) halve the S re-read traffic.
// ---------------------------------------------------------------------------
__global__ __launch_bounds__(512)
void gemm_out_kernel(const bf16* __restrict__ S, const bf16* __restrict__ Vpt,
                     float* __restrict__ out, const float* __restrict__ bs,
                     const float* __restrict__ feat,
                     const float* __restrict__ rsum, double* __restrict__ stats)
{
    __shared__ bf16 As[128 * 64];
    __shared__ bf16 Bs[128 * 64];
    __shared__ float red[16];
    const int id = blockIdx.x;
    const int xcd = id & 7, s = id >> 3;             // s in [0,32)
    const int bz = xcd >> 1;
    const int n0 = (s & 3) * 128;                    // 4 c'-tiles
    const int m0 = (((xcd & 1) << 3) + (s >> 2)) * 128;  // 8 t-tiles per half
    f32x4 acc[2][4] = {};
    CO::run(S + (long)bz * TTT, Vpt + (long)bz * CT, 2048, m0, n0, As, Bs, acc);

    const int tid = threadIdx.x;
    const int lane = tid & 63, wid = tid >> 6;
    const int wr = (wid / 2) * 32, wc = (wid % 2) * 64;
    const int lm = lane & 15, lq = lane >> 4;
    const float* rsb = rsum + (long)bz * TT;
    float inv[2][4];
#pragma unroll
    for (int mi = 0; mi < 2; ++mi) {
        int mrow = m0 + wr + mi * 16 + lq * 4;
        f32x4 rv = *(const f32x4*)(rsb + mrow);
#pragma unroll
        for (int r = 0; r < 4; ++r) inv[mi][r] = 1.f / rv[r];
    }
    float s1 = 0.f, s2 = 0.f;
#pragma unroll
    for (int mi = 0; mi < 2; ++mi)
#pragma unroll
        for (int ni = 0; ni < 4; ++ni) {
            int mrow = m0 + wr + mi * 16 + lq * 4;   // t, 4 contiguous
            int n = n0 + wc + ni * 16 + lm;          // c'
            long off = (long)bz * CT + (long)n * TT + mrow;
            f32x4 fv = *(const f32x4*)(feat + off);
            float bn = bs[n];
            f32x4 res;
#pragma unroll
            for (int r = 0; r < 4; ++r) {
                float v = acc[mi][ni][r] * inv[mi][r] + bn + fv[r];
                res[r] = v;
                s1 += v;
                s2 += v * v;
            }
            *(f32x4*)(out + off) = res;
        }
#pragma unroll
    for (int off = 32; off; off >>= 1) {
        s1 += __shfl_xor(s1, off, 64);
        s2 += __shfl_xor(s2, off, 64);
    }
    if (lane == 0) { red[wid] = s1; red[8 + wid] = s2; }
    __syncthreads();
    if (tid == 0) {
        double t1 = 0.0, t2 = 0.0;
#pragma unroll
        for (int w = 0; w < 8; ++w) { t1 += red[w]; t2 += red[8 + w]; }
        atomicAdd(stats + bz * 2, t1);
        atomicAdd(stats + bz * 2 + 1, t2);
    }
}

// ---------------------------------------------------------------------------
// Fused prep, 1D grid of 4624 blocks x 256 threads:
//  blk < 4096 : featT transpose tile + per-tile column sums into frp.
//  4096..4479 : Wq|Wv|Ws fp32 -> bf16.
//  4480..4623 : wkc/wvl/wlbv precomputes; zero stats/qb/u/rsum/vl.
// ---------------------------------------------------------------------------
__global__ __launch_bounds__(256)
void prep_kernel(const float* __restrict__ feat, bf16* __restrict__ featT,
                 const float* __restrict__ Wq, const float* __restrict__ Wv,
                 const float* __restrict__ Ws, bf16* __restrict__ Wbf,
                 const float* __restrict__ Wk, const float* __restrict__ Wl,
                 const float* __restrict__ bv, float* __restrict__ wkc,
                 float* __restrict__ wvl, float* __restrict__ wlbv,
                 float* __restrict__ frp, float* __restrict__ qb,
                 float* __restrict__ u, float* __restrict__ rsum,
                 double* __restrict__ stats, float* __restrict__ vl)
{
    const int blk = blockIdx.x;
    const int tid = threadIdx.x;
    if (blk < 4096) {
        __shared__ float tile[32][33];
        __shared__ float sfr[4][32];
        const int b  = blk >> 10;
        const int c0 = ((blk & 1023) >> 6) * 32;
        const int tt = blk & 63;           // t-tile index
        const int t0 = tt * 32;
        const int tx = tid & 31;
        const int ty = tid >> 5;   // 0..7
#pragma unroll
        for (int j = 0; j < 4; ++j) {
            int c = c0 + ty + j * 8;
            tile[ty + j * 8][tx] = feat[(long)b * CT + (long)c * TT + t0 + tx];
        }
        __syncthreads();
        float ps = 0.f;
#pragma unroll
        for (int j = 0; j < 4; ++j) {
            int tl = ty + j * 8;
            int t = t0 + tl;
            int c = c0 + tx;
            float v = tile[tx][tl];
            ps += v;
            featT[(long)b * TC + (long)t * CC + c] = (bf16)v;
        }
        const int wid = tid >> 6;
        ps += __shfl_xor(ps, 32, 64);
        if ((tid & 63) < 32) sfr[wid][tx] = ps;
        __syncthreads();
        if (tid < 32) {
            float s = sfr[0][tid] + sfr[1][tid] + sfr[2][tid] + sfr[3][tid];
            frp[(((long)b * 64 + tt) << 9) + c0 + tid] = s;   // own slice, no atomic
        }
    } else if (blk < 4480) {
        long gid = (long)(blk - 4096) * 256 + tid;
        long idx = gid * 8;
        int w = (int)(idx >> 18);
        long off = idx & 262143;
        const float* src = (w == 0) ? Wq : (w == 1) ? Wv : Ws;
        f32x4 a = *(const f32x4*)(src + off);
        f32x4 b = *(const f32x4*)(src + off + 4);
        bf16x8 o;
#pragma unroll
        for (int j = 0; j < 4; ++j) { o[j] = (bf16)a[j]; o[4 + j] = (bf16)b[j]; }
        *(bf16x8*)(Wbf + idx) = o;
    } else {
        int mid = (blk - 4480) * 256 + tid;   // [0, 36864)
        if (mid < 512) {
            float s = 0.f;
            for (int o = 0; o < 512; ++o) s += Wk[o * 512 + mid];
            wkc[mid] = s;
        } else if (mid < 1024) {
            int k = mid - 512;
            float s = 0.f;
            for (int c = 0; c < 512; ++c) s += Wl[c] * Wv[c * 512 + k];
            wvl[k] = s;
        } else if (mid < 1088) {
            int lane = mid - 1024;
            float s = 0.f;
#pragma unroll
            for (int j = 0; j < 8; ++j) s += Wl[lane + 64 * j] * bv[lane + 64 * j];
#pragma unroll
            for (int off = 32; off; off >>= 1) s += __shfl_xor(s, off, 64);
            if (lane == 0) wlbv[0] = s;
        } else if (mid >= 1152 && mid < 1160) {
            stats[mid - 1152] = 0.0;
        } else if (mid >= 4096 && mid < 12288) {
            qb[mid - 4096] = 0.f;
        } else if (mid >= 12288 && mid < 20480) {
            u[mid - 12288] = 0.f;
        } else if (mid >= 20480 && mid < 28672) {
            rsum[mid - 20480] = 0.f;
        } else if (mid >= 28672 && mid < 36864) {
            vl[mid - 28672] = 0.f;
        }
    }
}

// ---------------------------------------------------------------------------
// blocks <4096: LayerNorm finalize in place on d_out.
// blocks 4096..4099: f_score[b][t]; u_raw must be normalized by rsum here.
// ---------------------------------------------------------------------------
__global__ __launch_bounds__(256)
void ln_score_kernel(float* __restrict__ out, const double* __restrict__ stats,
                     const float* __restrict__ u, const float* __restrict__ frp,
                     const float* __restrict__ wvl, const float* __restrict__ wlbv,
                     const float* __restrict__ blp, const float* __restrict__ rsum)
{
    if (blockIdx.x < 4096) {
        long i = ((long)blockIdx.x * 256 + threadIdx.x) * 4;
        int b = (int)(i >> 20);            // C*T = 2^20
        const double n = 1048576.0;
        double mu  = stats[b * 2] / n;
        double var = stats[b * 2 + 1] / n - mu * mu;
        float rs = (float)(1.0 / sqrt(var + 1e-5));
        float muf = (float)mu;
        f32x4 v = *(f32x4*)(out + i);
#pragma unroll
        for (int j = 0; j < 4; ++j) v[j] = (v[j] - muf) * rs;
        *(f32x4*)(out + i) = v;
    } else {
        const int b = blockIdx.x - 4096;
        __shared__ float ssv[4];
        const int tid = threadIdx.x, lane = tid & 63, wid = tid >> 6;
        const float* fb = frp + ((long)b * 64 << 9);
        float s0 = 0.f, s1 = 0.f;
#pragma unroll 8
        for (int k = 0; k < 64; ++k) {
            s0 += fb[(k << 9) + tid];
            s1 += fb[(k << 9) + tid + 256];
        }
        float p = s0 * wvl[tid] + s1 * wvl[tid + 256];
#pragma unroll
        for (int off = 32; off; off >>= 1) p += __shfl_xor(p, off, 64);
        if (lane == 0) ssv[wid] = p;
        __syncthreads();
        const float sv = ssv[0] + ssv[1] + ssv[2] + ssv[3] + 2048.f * wlbv[0];
        const float bl0 = blp[0];
#pragma unroll
        for (int j = 0; j < 8; ++j) {
            int t = tid + j * 256;
            float uu = u[(long)b * TT + t] / rsum[(long)b * TT + t];
            float uf = uu + bl0;
            float vf = sv - uu + bl0;
            float fs  = 1.f / (1.f + __expf(-uf));
            float bsc = 1.f - 1.f / (1.f + __expf(-vf));
            out[(long)BB * CT + (long)b * TT + t] = 0.5f * (fs + bsc);
        }
    }
}

// ---------------------------------------------------------------------------
extern "C" void kernel_launch(void* const* d_in, const int* in_sizes, int n_in,
                              void* d_out, int out_size, void* d_ws, size_t ws_size,
                              hipStream_t stream)
{
    const float* feat = (const float*)d_in[0];
    const float* Wq   = (const float*)d_in[1];
    const float* bq   = (const float*)d_in[2];
    const float* Wk   = (const float*)d_in[3];
    const float* bk   = (const float*)d_in[4];
    const float* Wv   = (const float*)d_in[5];
    const float* bv   = (const float*)d_in[6];
    const float* Ws   = (const float*)d_in[7];
    const float* bs   = (const float*)d_in[8];
    const float* Wl   = (const float*)d_in[9];
    const float* bl   = (const float*)d_in[10];
    float* out = (float*)d_out;

    // workspace layout (bytes)
    if (ws_size < 69316736) return;
    char* ws = (char*)d_ws;
    bf16* featT  = (bf16*)(ws);                  //  8,388,608  [B][T][C]
    bf16* Wbf    = (bf16*)(ws + 8388608);        //  1,572,864  Wq|Wv|Ws bf16
    bf16* Qb     = (bf16*)(ws + 9961472);        //  8,388,608  [B][T][C]  (Q' = Q*wkc)
    bf16* Vn     = (bf16*)(ws + 18350080);       //  8,388,608  [B][T][C]  V natural
    bf16* Vpt    = (bf16*)(ws + 26738688);       //  8,388,608  [B][C][T]  V' = Ws.V^T
    float* vl    = (float*)(ws + 26738688);      //  32,768     [B][T] V·Wl — ALIASES
                                                 //  Vpt head; read by gemm_s BEFORE
                                                 //  gemm_vs overwrites (stream order)
    bf16* S      = (bf16*)(ws + 35127296);       // 33,554,432  [B][T][T] P = exp(s)
    float* wkc   = (float*)(ws + 68689920);      //  2,048
    float* wvl   = (float*)(ws + 68691968);      //  2,048
    float* wlbv  = (float*)(ws + 68694016);      //  64 (8 used)
    float* qb    = (float*)(ws + 68694080);      // 32,768      [B][T] = Q.bk row-dots
    double* stats= (double*)(ws + 68726848);     //  64         [B][2] sum,sumsq
    float* u     = (float*)(ws + 68726912);      // 32,768      [B][T] = P.vl row-dots
    float* rsum  = (float*)(ws + 68759680);      // 32,768      [B][T] = exp row-sums
    float* frp   = (float*)(ws + 68792448);      // 524,288     [B][64][C] feat col-sums

    bf16* Wq_bf = Wbf;
    bf16* Wv_bf = Wbf + 262144;
    bf16* Ws_bf = Wbf + 524288;

    // transpose + weight-cast + small precomputes, one dispatch
    prep_kernel<<<4624, 256, 0, stream>>>(feat, featT, Wq, Wv, Ws, Wbf, Wk, Wl, bv,
                                          wkc, wvl, wlbv, frp, qb, u, rsum, stats, vl);
    // Q' and Vn with shared featT staging; V-half also accumulates vl = V·Wl
    gemm_qv_kernel<<<dim3(8, 16, 4), 512, 0, stream>>>(
        featT, Wq_bf, Wv_bf, Qb, Vn, bq, bv, wkc, bk, qb, Wl, vl);
    // P = exp(...) + rsum + u_raw atomics (8-phase 256^2); reads vl
    gemm_s256_kernel<<<256, 512, 0, stream>>>(Qb, featT, S, qb, rsum, vl, u);
    // V' = Ws.V^T  (overwrites the vl alias region — must run after gemm_s)
    gemm_vs_kernel<<<256, 512, 0, stream>>>(Vn, Ws_bf, Vpt);
    // out = feat + (P.V')/rsum + bs + LN stats  (fused old gemm_y+gemm_final)
    gemm_out_kernel<<<256, 512, 0, stream>>>(S, Vpt, out, bs, feat, rsum, stats);
    ln_score_kernel<<<4100, 256, 0, stream>>>(out, stats, u, frp, wvl, wlbv, bl, rsum);
}

// Round 3
// 211.668 us; speedup vs baseline: 1.0491x; 1.0491x over previous
//
#include <hip/hip_runtime.h>
#include <hip/hip_bf16.h>

// Problem constants
#define BB 4
#define CC 512
#define TT 2048
static constexpr long CT  = (long)CC * TT;   // 1048576 = 2^20
static constexpr long TC  = (long)TT * CC;
static constexpr long TTT = (long)TT * TT;   // 4194304
static constexpr float SM_SCALE = 0.04419417382415922f; // 1/sqrt(512)

typedef __bf16 bf16;
typedef __attribute__((ext_vector_type(8))) __bf16 bf16x8;
typedef __attribute__((ext_vector_type(4))) __bf16 bf16x4;
typedef __attribute__((ext_vector_type(4))) float f32x4;

// Async global->LDS, 16B per lane. LDS dest must be wave-uniform base + lane*16.
__device__ __forceinline__ void load_lds16(const bf16* g, bf16* l)
{
    __builtin_amdgcn_global_load_lds(
        (const __attribute__((address_space(1))) void*)g,
        (__attribute__((address_space(3))) void*)l, 16, 0, 0);
}

#define FENCE asm volatile("" ::: "memory")

// ---------------------------------------------------------------------------
// Pipelined NT-GEMM core (T3/T4 minimum form): acc[m][n] += sum_k A[m][k]*B[n][k]
// (k-contig, ld==K). XOR-swizzled LDS, double-buffered, depth-2 prefetch with
// counted vmcnt(4) — loads for tile t+1 stay in flight across a full MFMA
// phase; never drained to 0 in steady state. Fixes the 1-block/CU latency
// exposure of the old 2-barrier drain structure (gemm_out was 42 µs at
// MfmaUtil=14%, Occ=16%: pure latency-bound).
// Per K-tile:
//   ds_read frags -> lgkmcnt(0)+sched_barrier -> barrier (buf p reads retired)
//   -> stage(t+2 -> buf p) -> setprio(1) MFMAx16 setprio(0)
//   -> vmcnt(4) (t+1 landed, t+2 flying) -> barrier.
// ---------------------------------------------------------------------------
template <int TM, int TN, int WR, int WC, int BK>
struct CorePipe {
    static constexpr int THREADS = WR * WC * 64;
    static constexpr int MI = TM / (WR * 16);
    static constexpr int NI = TN / (WC * 16);
    static constexpr int CPR = BK / 8;
    static constexpr int RSH = (BK == 64) ? 3 : 2;
    static constexpr int CMASK = CPR - 1;
    static constexpr int CHUNKS = (TM + TN) * CPR;
    static constexpr int ACH = TM * CPR;
    static constexpr int CPT = CHUNKS / THREADS;
    static_assert(CPT * THREADS == CHUNKS, "chunk divisibility");
    static_assert(CPT == 4, "vmcnt literals below assume 4 loads/thread/tile");

    __device__ static __forceinline__ void stage(
        const bf16* __restrict__ Ab, const bf16* __restrict__ Bb,
        int K, int m0, int n0, int t, int p, bf16* As, bf16* Bs, int tid)
    {
#pragma unroll
        for (int i = 0; i < CPT; ++i) {
            int c = tid + i * THREADS;
            if (c < ACH) {
                int row = c >> RSH;
                int gc  = (c & CMASK) ^ (row & CMASK);
                load_lds16(Ab + (long)(m0 + row) * K + t * BK + gc * 8,
                           As + p * (TM * BK) + c * 8);
            } else {
                int d = c - ACH;
                int row = d >> RSH;
                int gc  = (d & CMASK) ^ (row & CMASK);
                load_lds16(Bb + (long)(n0 + row) * K + t * BK + gc * 8,
                           Bs + p * (TN * BK) + d * 8);
            }
        }
    }

    // As/Bs must each hold 2 * T{M,N} * BK bf16 (double buffer).
    __device__ static __forceinline__ void run(
        const bf16* __restrict__ Ab, const bf16* __restrict__ Bb,
        int K, int m0, int n0, bf16* As, bf16* Bs, f32x4 (&acc)[MI][NI])
    {
        const int tid  = threadIdx.x;
        const int lane = tid & 63;
        const int wid  = tid >> 6;
        const int wr = (wid / WC) * (MI * 16);
        const int wc = (wid % WC) * (NI * 16);
        const int lm = lane & 15;
        const int lq = lane >> 4;
        const int nt = K / BK;

        stage(Ab, Bb, K, m0, n0, 0, 0, As, Bs, tid);
        stage(Ab, Bb, K, m0, n0, 1, 1, As, Bs, tid);
        asm volatile("s_waitcnt vmcnt(4)" ::: "memory");  // tile0 landed
        FENCE; __builtin_amdgcn_s_barrier(); FENCE;

        for (int t = 0; t < nt; ++t) {
            const int p = t & 1;
            const bf16* Ap = As + p * (TM * BK);
            const bf16* Bp = Bs + p * (TN * BK);
            bf16x8 af[BK / 32][MI], bfr[BK / 32][NI];
#pragma unroll
            for (int ks = 0; ks < BK / 32; ++ks) {
#pragma unroll
                for (int i = 0; i < MI; ++i) {
                    int ar = wr + i * 16 + lm;
                    int cc = (ks * 4 + lq) ^ (ar & CMASK);
                    af[ks][i] = *(const bf16x8*)(Ap + ar * BK + cc * 8);
                }
#pragma unroll
                for (int i = 0; i < NI; ++i) {
                    int br = wc + i * 16 + lm;
                    int cc = (ks * 4 + lq) ^ (br & CMASK);
                    bfr[ks][i] = *(const bf16x8*)(Bp + br * BK + cc * 8);
                }
            }
            asm volatile("s_waitcnt lgkmcnt(0)" ::: "memory"); // my reads retired
            __builtin_amdgcn_sched_barrier(0);
            FENCE; __builtin_amdgcn_s_barrier(); FENCE;        // ALL reads retired
            if (t + 2 < nt)
                stage(Ab, Bb, K, m0, n0, t + 2, p, As, Bs, tid); // refill freed buf
            __builtin_amdgcn_s_setprio(1);
#pragma unroll
            for (int ks = 0; ks < BK / 32; ++ks)
#pragma unroll
                for (int mi = 0; mi < MI; ++mi)
#pragma unroll
                    for (int ni = 0; ni < NI; ++ni)
                        acc[mi][ni] = __builtin_amdgcn_mfma_f32_16x16x32_bf16(
                            af[ks][mi], bfr[ks][ni], acc[mi][ni], 0, 0, 0);
            __builtin_amdgcn_s_setprio(0);
            if (t + 1 < nt) {
                if (t + 2 < nt)
                    asm volatile("s_waitcnt vmcnt(4)" ::: "memory"); // t+1 landed
                else
                    asm volatile("s_waitcnt vmcnt(0)" ::: "memory");
                FENCE; __builtin_amdgcn_s_barrier(); FENCE;
            }
        }
    }
};

using CP = CorePipe<128, 128, 4, 2, 64>;   // 8-wave 128x128 pipelined workhorse

// ---------------------------------------------------------------------------
// QV core, pipelined the same way. 128-row B tile staged from TWO pointers:
// rows 0..63 from Bq (Wq slab), rows 64..127 from Bv (Wv slab). One shared A
// (featT) staging feeds both Q and V GEMMs. K fixed at 512.
// ---------------------------------------------------------------------------
struct CoreQVPipe {
    static constexpr int THREADS = 512;
    static constexpr int MI = 2;
    static constexpr int NI = 4;
    static constexpr int BK = 64;
    static constexpr int CPR = 8, RSH = 3, CMASK = 7;
    static constexpr int ACH = 128 * 8;          // A chunks
    static constexpr int CHUNKS = 256 * 8;       // A + B
    static constexpr int CPT = CHUNKS / THREADS; // 4

    __device__ static __forceinline__ void stage(
        const bf16* __restrict__ Ab, const bf16* __restrict__ Bq,
        const bf16* __restrict__ Bv, int m0, int t, int p,
        bf16* As, bf16* Bs, int tid)
    {
#pragma unroll
        for (int i = 0; i < CPT; ++i) {
            int c = tid + i * THREADS;
            if (c < ACH) {
                int row = c >> RSH;
                int gc  = (c & CMASK) ^ (row & CMASK);
                load_lds16(Ab + (long)(m0 + row) * 512 + t * 64 + gc * 8,
                           As + p * (128 * 64) + c * 8);
            } else {
                int d = c - ACH;
                int row = d >> RSH;
                int gc  = (d & CMASK) ^ (row & CMASK);
                const bf16* src = (row < 64)
                    ? Bq + (long)row * 512
                    : Bv + (long)(row - 64) * 512;
                load_lds16(src + t * 64 + gc * 8, Bs + p * (128 * 64) + d * 8);
            }
        }
    }

    __device__ static __forceinline__ void run(
        const bf16* __restrict__ Ab, const bf16* __restrict__ Bq,
        const bf16* __restrict__ Bv,
        int m0, bf16* As, bf16* Bs, f32x4 (&acc)[MI][NI])
    {
        const int tid  = threadIdx.x;
        const int lane = tid & 63;
        const int wid  = tid >> 6;
        const int wr = (wid / 2) * 32;
        const int wc = (wid % 2) * 64;
        const int lm = lane & 15;
        const int lq = lane >> 4;
        const int nt = 8;                      // 512 / 64

        stage(Ab, Bq, Bv, m0, 0, 0, As, Bs, tid);
        stage(Ab, Bq, Bv, m0, 1, 1, As, Bs, tid);
        asm volatile("s_waitcnt vmcnt(4)" ::: "memory");
        FENCE; __builtin_amdgcn_s_barrier(); FENCE;

        for (int t = 0; t < nt; ++t) {
            const int p = t & 1;
            const bf16* Ap = As + p * (128 * 64);
            const bf16* Bp = Bs + p * (128 * 64);
            bf16x8 af[2][MI], bfr[2][NI];
#pragma unroll
            for (int ks = 0; ks < 2; ++ks) {
#pragma unroll
                for (int i = 0; i < MI; ++i) {
                    int ar = wr + i * 16 + lm;
                    int cc = (ks * 4 + lq) ^ (ar & CMASK);
                    af[ks][i] = *(const bf16x8*)(Ap + ar * BK + cc * 8);
                }
#pragma unroll
                for (int i = 0; i < NI; ++i) {
                    int br = wc + i * 16 + lm;
                    int cc = (ks * 4 + lq) ^ (br & CMASK);
                    bfr[ks][i] = *(const bf16x8*)(Bp + br * BK + cc * 8);
                }
            }
            asm volatile("s_waitcnt lgkmcnt(0)" ::: "memory");
            __builtin_amdgcn_sched_barrier(0);
            FENCE; __builtin_amdgcn_s_barrier(); FENCE;
            if (t + 2 < nt)
                stage(Ab, Bq, Bv, m0, t + 2, p, As, Bs, tid);
            __builtin_amdgcn_s_setprio(1);
#pragma unroll
            for (int ks = 0; ks < 2; ++ks)
#pragma unroll
                for (int mi = 0; mi < MI; ++mi)
#pragma unroll
                    for (int ni = 0; ni < NI; ++ni)
                        acc[mi][ni] = __builtin_amdgcn_mfma_f32_16x16x32_bf16(
                            af[ks][mi], bfr[ks][ni], acc[mi][ni], 0, 0, 0);
            __builtin_amdgcn_s_setprio(0);
            if (t + 1 < nt) {
                if (t + 2 < nt)
                    asm volatile("s_waitcnt vmcnt(4)" ::: "memory");
                else
                    asm volatile("s_waitcnt vmcnt(0)" ::: "memory");
                FENCE; __builtin_amdgcn_s_barrier(); FENCE;
            }
        }
    }
};

// ---------------------------------------------------------------------------
// Q+V with ONE shared featT staging. Even waves (wc=0) hold the Q half; odd
// waves (wc=64) the V half. V stored in NATURAL layout Vn[b][s][c]; the V half
// also accumulates vl[b][s] = V[s]·Wl (f32 atomics) for the u = P·vl identity.
// ---------------------------------------------------------------------------
__global__ __launch_bounds__(512)
void gemm_qv_kernel(const bf16* __restrict__ featT, const bf16* __restrict__ Wq_bf,
                    const bf16* __restrict__ Wv_bf, bf16* __restrict__ Qb,
                    bf16* __restrict__ Vn, const float* __restrict__ bq,
                    const float* __restrict__ bv, const float* __restrict__ wkc,
                    const float* __restrict__ bk, float* __restrict__ qb,
                    const float* __restrict__ Wl, float* __restrict__ vl)
{
    __shared__ __align__(16) bf16 As[2 * 128 * 64];
    __shared__ __align__(16) bf16 Bs[2 * 128 * 64];
    const int rb = blockIdx.z;
    const int m0 = blockIdx.y * 128;
    const int ng = blockIdx.x;               // channel group [ng*64, ng*64+64)
    const long wofs = (long)(ng * 64) * 512;
    f32x4 acc[2][4] = {};
    CoreQVPipe::run(featT + (long)rb * TC, Wq_bf + wofs, Wv_bf + wofs, m0, As, Bs, acc);

    const int lane = threadIdx.x & 63, wid = threadIdx.x >> 6;
    const int wr = (wid / 2) * 32;
    const bool isV = wid & 1;
    const int lm = lane & 15, lq = lane >> 4;

    if (isV) {
        bf16* outV = Vn + (long)rb * TC;
        float* vlb = vl + (long)rb * TT;
        float vs_[2][4] = {};
#pragma unroll
        for (int mi = 0; mi < 2; ++mi)
#pragma unroll
            for (int ni = 0; ni < 4; ++ni) {
                int n = ng * 64 + ni * 16 + lm;
                float bn = bv[n], wn = Wl[n];
#pragma unroll
                for (int r = 0; r < 4; ++r) {
                    int m = m0 + wr + mi * 16 + lq * 4 + r;
                    float v = acc[mi][ni][r] + bn;
                    outV[(long)m * 512 + n] = (bf16)v;
                    vs_[mi][r] += v * wn;
                }
            }
#pragma unroll
        for (int mi = 0; mi < 2; ++mi)
#pragma unroll
            for (int r = 0; r < 4; ++r) {
                float s = vs_[mi][r];
                s += __shfl_xor(s, 1, 64); s += __shfl_xor(s, 2, 64);
                s += __shfl_xor(s, 4, 64); s += __shfl_xor(s, 8, 64);
                if (lm == 0)
                    atomicAdd(vlb + m0 + wr + mi * 16 + lq * 4 + r, s);
            }
    } else {
        bf16* out = Qb + (long)rb * TC;
        float* qbb = qb + (long)rb * TT;
        float rs[2][4] = {};
#pragma unroll
        for (int mi = 0; mi < 2; ++mi)
#pragma unroll
            for (int ni = 0; ni < 4; ++ni) {
                int n = ng * 64 + ni * 16 + lm;
                float bn = bq[n], wn = wkc[n], kn = bk[n];
#pragma unroll
                for (int r = 0; r < 4; ++r) {
                    int m = m0 + wr + mi * 16 + lq * 4 + r;
                    float v = acc[mi][ni][r] + bn;
                    rs[mi][r] += v * kn;
                    out[(long)m * 512 + n] = (bf16)(v * wn);
                }
            }
#pragma unroll
        for (int mi = 0; mi < 2; ++mi)
#pragma unroll
            for (int r = 0; r < 4; ++r) {
                float s = rs[mi][r];
                s += __shfl_xor(s, 1, 64); s += __shfl_xor(s, 2, 64);
                s += __shfl_xor(s, 4, 64); s += __shfl_xor(s, 8, 64);
                if (lm == 0)
                    atomicAdd(qbb + m0 + wr + mi * 16 + lq * 4 + r, s);
            }
    }
}

// ---------------------------------------------------------------------------
// P = exp((Q'.featT^T + qb) * SM_SCALE) (UNNORMALIZED) + rsum atomics +
// u_raw atomics (u_raw[t] = sum_s P[t][s]*vl[s]; y·Wl = u_raw/rsum).
// 256x256 tile, 8 waves, 128 KiB double-buffered LDS, 8-phase schedule with
// counted vmcnt(4) (T3+T4) + setprio around MFMA clusters (T5).
// ---------------------------------------------------------------------------
__global__ __launch_bounds__(512, 2)
void gemm_s256_kernel(const bf16* __restrict__ Qb, const bf16* __restrict__ featT,
                      bf16* __restrict__ S, const float* __restrict__ qb,
                      float* __restrict__ rsum, const float* __restrict__ vl,
                      float* __restrict__ u)
{
    // [kbuf parity][op A=0/B=1][256 rows * 64 k], 128 KiB total
    __shared__ __align__(16) bf16 lds[2][2][256 * 64];
    const int id   = blockIdx.x;
    const int xcd  = id & 7, sIdx = id >> 3;         // sIdx in [0,32)
    const int bz   = xcd >> 1;
    const int n0   = (sIdx & 7) * 256;               // 8 n-tiles
    const int m0   = (((xcd & 1) << 2) + (sIdx >> 3)) * 256; // 4 m-tiles/half
    const bf16* __restrict__ Ab = Qb + (long)bz * TC;
    const bf16* __restrict__ Bb = featT + (long)bz * TC;

    const int tid  = threadIdx.x;
    const int lane = tid & 63;
    const int wid  = tid >> 6;
    const int lm = lane & 15, lq = lane >> 4;
    const int wrb = (wid >> 2) * 64;   // wave row sub-base within each 128-half
    const int wcb = (wid & 3) * 32;    // wave col sub-base within each 128-half

    f32x4 acc[8][4] = {};

#define STAGE_HT(t, op, h)                                                    \
    do {                                                                      \
        const bf16* gp_ = (op) ? Bb : Ab;                                     \
        const int  br_  = ((op) ? n0 : m0) + (h) * 128;                       \
        bf16* lp_ = &lds[(t) & 1][op][(h) * 128 * 64];                        \
        _Pragma("unroll")                                                     \
        for (int i_ = 0; i_ < 2; ++i_) {                                      \
            int c_ = tid + i_ * 512;                                          \
            int r_ = c_ >> 3;                                                 \
            int g_ = (c_ & 7) ^ (r_ & 7);                                     \
            load_lds16(gp_ + (long)(br_ + r_) * 512 + (t) * 64 + g_ * 8,      \
                       lp_ + c_ * 8);                                         \
        }                                                                     \
    } while (0)

#define PHASE(t, qm, qn, doSt, st, sop, sh, doVm)                             \
    do {                                                                      \
        bf16x8 af[2][4], bfr[2][2];                                           \
        const bf16* Al_ = lds[(t) & 1][0];                                    \
        const bf16* Bl_ = lds[(t) & 1][1];                                    \
        _Pragma("unroll")                                                     \
        for (int ks = 0; ks < 2; ++ks) {                                      \
            _Pragma("unroll")                                                 \
            for (int j = 0; j < 4; ++j) {                                     \
                int ar = (qm) * 128 + wrb + j * 16 + lm;                      \
                int cc = (ks * 4 + lq) ^ (ar & 7);                            \
                af[ks][j] = *(const bf16x8*)(Al_ + ar * 64 + cc * 8);         \
            }                                                                 \
            _Pragma("unroll")                                                 \
            for (int j = 0; j < 2; ++j) {                                     \
                int br = (qn) * 128 + wcb + j * 16 + lm;                      \
                int cc = (ks * 4 + lq) ^ (br & 7);                            \
                bfr[ks][j] = *(const bf16x8*)(Bl_ + br * 64 + cc * 8);        \
            }                                                                 \
        }                                                                     \
        if (doSt) STAGE_HT(st, sop, sh);                                      \
        if (doVm) {                                                           \
            if ((t) < 6) asm volatile("s_waitcnt vmcnt(4)" ::: "memory");     \
            else         asm volatile("s_waitcnt vmcnt(0)" ::: "memory");     \
        }                                                                     \
        FENCE; __builtin_amdgcn_s_barrier(); FENCE;                           \
        __builtin_amdgcn_s_setprio(1);                                        \
        _Pragma("unroll")                                                     \
        for (int ks = 0; ks < 2; ++ks)                                        \
            _Pragma("unroll")                                                 \
            for (int j = 0; j < 4; ++j)                                       \
                _Pragma("unroll")                                             \
                for (int j2 = 0; j2 < 2; ++j2)                                \
                    acc[(qm) * 4 + j][(qn) * 2 + j2] =                        \
                        __builtin_amdgcn_mfma_f32_16x16x32_bf16(              \
                            af[ks][j], bfr[ks][j2],                           \
                            acc[(qm) * 4 + j][(qn) * 2 + j2], 0, 0, 0);       \
        __builtin_amdgcn_s_setprio(0);                                        \
        FENCE; __builtin_amdgcn_s_barrier(); FENCE;                           \
    } while (0)

    STAGE_HT(0, 0, 0); STAGE_HT(0, 1, 0); STAGE_HT(0, 0, 1); STAGE_HT(0, 1, 1);
    STAGE_HT(1, 0, 0); STAGE_HT(1, 1, 0);
    asm volatile("s_waitcnt vmcnt(4)" ::: "memory");
    FENCE; __builtin_amdgcn_s_barrier(); FENCE;

    for (int t = 0; t < 8; ++t) {
        PHASE(t, 0, 0, t + 1 < 8, t + 1, 0, 1, false); // stage A-hi(t+1)
        PHASE(t, 0, 1, t + 1 < 8, t + 1, 1, 1, false); // stage B-hi(t+1)
        PHASE(t, 1, 0, t + 2 < 8, t + 2, 0, 0, false); // stage A-lo(t+2)
        PHASE(t, 1, 1, t + 2 < 8, t + 2, 1, 0, true);  // stage B-lo(t+2)+vmcnt
    }
#undef PHASE
#undef STAGE_HT

    // Epilogue: exp, bf16 store, rsum + u_raw row atomics.
    bf16* outp = S + (long)bz * TTT;
    const float* qbb = qb + (long)bz * TT;
    const float* vlb = vl + (long)bz * TT;
    float* rsb = rsum + (long)bz * TT;
    float* ub  = u + (long)bz * TT;
#pragma unroll
    for (int mi = 0; mi < 8; ++mi) {
        const int mrow = m0 + (mi >> 2) * 128 + wrb + (mi & 3) * 16 + lq * 4;
        const f32x4 qv = *(const f32x4*)(qbb + mrow);
        float rp[4] = {0.f, 0.f, 0.f, 0.f};
        float up[4] = {0.f, 0.f, 0.f, 0.f};
#pragma unroll
        for (int ni = 0; ni < 4; ++ni) {
            const int ncol = n0 + (ni >> 1) * 128 + wcb + (ni & 1) * 16 + lm;
            const float vlv = vlb[ncol];
#pragma unroll
            for (int r = 0; r < 4; ++r) {
                float p = __expf((acc[mi][ni][r] + qv[r]) * SM_SCALE);
                outp[(long)(mrow + r) * 2048 + ncol] = (bf16)p;
                rp[r] += p;
                up[r] += p * vlv;
            }
        }
#pragma unroll
        for (int r = 0; r < 4; ++r) {
            float s2 = rp[r], s3 = up[r];
            s2 += __shfl_xor(s2, 1, 64); s2 += __shfl_xor(s2, 2, 64);
            s2 += __shfl_xor(s2, 4, 64); s2 += __shfl_xor(s2, 8, 64);
            s3 += __shfl_xor(s3, 1, 64); s3 += __shfl_xor(s3, 2, 64);
            s3 += __shfl_xor(s3, 4, 64); s3 += __shfl_xor(s3, 8, 64);
            if (lm == 0) {
                atomicAdd(rsb + mrow + r, s2);
                atomicAdd(ub + mrow + r, s3);
            }
        }
    }
}

// ---------------------------------------------------------------------------
// V't[b][c'][s] = sum_c Ws[c'][c] * Vn[b][s][c]   (NT: A=Ws rows, B=Vn rows).
// 256 blocks; per batch 4 m-tiles (c') x 16 n-tiles (s). Pipelined core.
// ---------------------------------------------------------------------------
__global__ __launch_bounds__(512)
void gemm_vs_kernel(const bf16* __restrict__ Vn, const bf16* __restrict__ Ws_bf,
                    bf16* __restrict__ Vpt)
{
    __shared__ __align__(16) bf16 As[2 * 128 * 64];
    __shared__ __align__(16) bf16 Bs[2 * 128 * 64];
    const int id = blockIdx.x;
    const int xcd = id & 7, s = id >> 3;             // s in [0,32)
    const int bz = xcd >> 1;
    const int m0 = (((xcd & 1) << 1) + (s >> 4)) * 128;  // 4 c'-tiles
    const int n0 = (s & 15) * 128;                       // 16 s-tiles
    f32x4 acc[2][4] = {};
    CP::run(Ws_bf, Vn + (long)bz * TC, 512, m0, n0, As, Bs, acc);

    const int lane = threadIdx.x & 63, wid = threadIdx.x >> 6;
    const int wr = (wid / 2) * 32, wc = (wid % 2) * 64;
    const int lm = lane & 15, lq = lane >> 4;
    bf16* out = Vpt + (long)bz * CT;
#pragma unroll
    for (int mi = 0; mi < 2; ++mi)
#pragma unroll
        for (int ni = 0; ni < 4; ++ni) {
            int n = n0 + wc + ni * 16 + lm;
#pragma unroll
            for (int r = 0; r < 4; ++r) {
                int m = m0 + wr + mi * 16 + lq * 4 + r;
                out[(long)m * 2048 + n] = (bf16)acc[mi][ni][r];
            }
        }
}

// ---------------------------------------------------------------------------
// out[b][c'][t] = feat + (P·V't)/rsum[t] + bs[c'] + LN stats.
// A = S rows (k=s, K=2048), B = V't rows. 256 blocks, pipelined core.
// XCD ownership (bz=xcd>>1, t-half=xcd&1) matches gemm_s256's S writes.
// ---------------------------------------------------------------------------
__global__ __launch_bounds__(512)
void gemm_out_kernel(const bf16* __restrict__ S, const bf16* __restrict__ Vpt,
                     float* __restrict__ out, const float* __restrict__ bs,
                     const float* __restrict__ feat,
                     const float* __restrict__ rsum, double* __restrict__ stats)
{
    __shared__ __align__(16) bf16 As[2 * 128 * 64];
    __shared__ __align__(16) bf16 Bs[2 * 128 * 64];
    __shared__ float red[16];
    const int id = blockIdx.x;
    const int xcd = id & 7, s = id >> 3;             // s in [0,32)
    const int bz = xcd >> 1;
    const int n0 = (s & 3) * 128;                    // 4 c'-tiles
    const int m0 = (((xcd & 1) << 3) + (s >> 2)) * 128;  // 8 t-tiles per half
    f32x4 acc[2][4] = {};
    CP::run(S + (long)bz * TTT, Vpt + (long)bz * CT, 2048, m0, n0, As, Bs, acc);

    const int tid = threadIdx.x;
    const int lane = tid & 63, wid = tid >> 6;
    const int wr = (wid / 2) * 32, wc = (wid % 2) * 64;
    const int lm = lane & 15, lq = lane >> 4;
    const float* rsb = rsum + (long)bz * TT;
    float inv[2][4];
#pragma unroll
    for (int mi = 0; mi < 2; ++mi) {
        int mrow = m0 + wr + mi * 16 + lq * 4;
        f32x4 rv = *(const f32x4*)(rsb + mrow);
#pragma unroll
        for (int r = 0; r < 4; ++r) inv[mi][r] = 1.f / rv[r];
    }
    float s1 = 0.f, s2 = 0.f;
#pragma unroll
    for (int mi = 0; mi < 2; ++mi)
#pragma unroll
        for (int ni = 0; ni < 4; ++ni) {
            int mrow = m0 + wr + mi * 16 + lq * 4;   // t, 4 contiguous
            int n = n0 + wc + ni * 16 + lm;          // c'
            long off = (long)bz * CT + (long)n * TT + mrow;
            f32x4 fv = *(const f32x4*)(feat + off);
            float bn = bs[n];
            f32x4 res;
#pragma unroll
            for (int r = 0; r < 4; ++r) {
                float v = acc[mi][ni][r] * inv[mi][r] + bn + fv[r];
                res[r] = v;
                s1 += v;
                s2 += v * v;
            }
            *(f32x4*)(out + off) = res;
        }
#pragma unroll
    for (int off = 32; off; off >>= 1) {
        s1 += __shfl_xor(s1, off, 64);
        s2 += __shfl_xor(s2, off, 64);
    }
    if (lane == 0) { red[wid] = s1; red[8 + wid] = s2; }
    __syncthreads();
    if (tid == 0) {
        double t1 = 0.0, t2 = 0.0;
#pragma unroll
        for (int w = 0; w < 8; ++w) { t1 += red[w]; t2 += red[8 + w]; }
        atomicAdd(stats + bz * 2, t1);
        atomicAdd(stats + bz * 2 + 1, t2);
    }
}

// ---------------------------------------------------------------------------
// Fused prep, 1D grid of 4624 blocks x 256 threads:
//  blk < 4096 : featT transpose tile + per-tile column sums into frp.
//  4096..4479 : Wq|Wv|Ws fp32 -> bf16.
//  4480..4623 : wkc/wvl/wlbv precomputes; zero stats/qb/u/rsum/vl.
// ---------------------------------------------------------------------------
__global__ __launch_bounds__(256)
void prep_kernel(const float* __restrict__ feat, bf16* __restrict__ featT,
                 const float* __restrict__ Wq, const float* __restrict__ Wv,
                 const float* __restrict__ Ws, bf16* __restrict__ Wbf,
                 const float* __restrict__ Wk, const float* __restrict__ Wl,
                 const float* __restrict__ bv, float* __restrict__ wkc,
                 float* __restrict__ wvl, float* __restrict__ wlbv,
                 float* __restrict__ frp, float* __restrict__ qb,
                 float* __restrict__ u, float* __restrict__ rsum,
                 double* __restrict__ stats, float* __restrict__ vl)
{
    const int blk = blockIdx.x;
    const int tid = threadIdx.x;
    if (blk < 4096) {
        __shared__ float tile[32][33];
        __shared__ float sfr[4][32];
        const int b  = blk >> 10;
        const int c0 = ((blk & 1023) >> 6) * 32;
        const int tt = blk & 63;           // t-tile index
        const int t0 = tt * 32;
        const int tx = tid & 31;
        const int ty = tid >> 5;   // 0..7
#pragma unroll
        for (int j = 0; j < 4; ++j) {
            int c = c0 + ty + j * 8;
            tile[ty + j * 8][tx] = feat[(long)b * CT + (long)c * TT + t0 + tx];
        }
        __syncthreads();
        float ps = 0.f;
#pragma unroll
        for (int j = 0; j < 4; ++j) {
            int tl = ty + j * 8;
            int t = t0 + tl;
            int c = c0 + tx;
            float v = tile[tx][tl];
            ps += v;
            featT[(long)b * TC + (long)t * CC + c] = (bf16)v;
        }
        const int wid = tid >> 6;
        ps += __shfl_xor(ps, 32, 64);
        if ((tid & 63) < 32) sfr[wid][tx] = ps;
        __syncthreads();
        if (tid < 32) {
            float s = sfr[0][tid] + sfr[1][tid] + sfr[2][tid] + sfr[3][tid];
            frp[(((long)b * 64 + tt) << 9) + c0 + tid] = s;   // own slice, no atomic
        }
    } else if (blk < 4480) {
        long gid = (long)(blk - 4096) * 256 + tid;
        long idx = gid * 8;
        int w = (int)(idx >> 18);
        long off = idx & 262143;
        const float* src = (w == 0) ? Wq : (w == 1) ? Wv : Ws;
        f32x4 a = *(const f32x4*)(src + off);
        f32x4 b = *(const f32x4*)(src + off + 4);
        bf16x8 o;
#pragma unroll
        for (int j = 0; j < 4; ++j) { o[j] = (bf16)a[j]; o[4 + j] = (bf16)b[j]; }
        *(bf16x8*)(Wbf + idx) = o;
    } else {
        int mid = (blk - 4480) * 256 + tid;   // [0, 36864)
        if (mid < 512) {
            float s = 0.f;
            for (int o = 0; o < 512; ++o) s += Wk[o * 512 + mid];
            wkc[mid] = s;
        } else if (mid < 1024) {
            int k = mid - 512;
            float s = 0.f;
            for (int c = 0; c < 512; ++c) s += Wl[c] * Wv[c * 512 + k];
            wvl[k] = s;
        } else if (mid < 1088) {
            int lane = mid - 1024;
            float s = 0.f;
#pragma unroll
            for (int j = 0; j < 8; ++j) s += Wl[lane + 64 * j] * bv[lane + 64 * j];
#pragma unroll
            for (int off = 32; off; off >>= 1) s += __shfl_xor(s, off, 64);
            if (lane == 0) wlbv[0] = s;
        } else if (mid >= 1152 && mid < 1160) {
            stats[mid - 1152] = 0.0;
        } else if (mid >= 4096 && mid < 12288) {
            qb[mid - 4096] = 0.f;
        } else if (mid >= 12288 && mid < 20480) {
            u[mid - 12288] = 0.f;
        } else if (mid >= 20480 && mid < 28672) {
            rsum[mid - 20480] = 0.f;
        } else if (mid >= 28672 && mid < 36864) {
            vl[mid - 28672] = 0.f;
        }
    }
}

// ---------------------------------------------------------------------------
// blocks <4096: LayerNorm finalize in place on d_out.
// blocks 4096..4099: f_score[b][t]; u_raw normalized by rsum here.
// ---------------------------------------------------------------------------
__global__ __launch_bounds__(256)
void ln_score_kernel(float* __restrict__ out, const double* __restrict__ stats,
                     const float* __restrict__ u, const float* __restrict__ frp,
                     const float* __restrict__ wvl, const float* __restrict__ wlbv,
                     const float* __restrict__ blp, const float* __restrict__ rsum)
{
    if (blockIdx.x < 4096) {
        long i = ((long)blockIdx.x * 256 + threadIdx.x) * 4;
        int b = (int)(i >> 20);            // C*T = 2^20
        const double n = 1048576.0;
        double mu  = stats[b * 2] / n;
        double var = stats[b * 2 + 1] / n - mu * mu;
        float rs = (float)(1.0 / sqrt(var + 1e-5));
        float muf = (float)mu;
        f32x4 v = *(f32x4*)(out + i);
#pragma unroll
        for (int j = 0; j < 4; ++j) v[j] = (v[j] - muf) * rs;
        *(f32x4*)(out + i) = v;
    } else {
        const int b = blockIdx.x - 4096;
        __shared__ float ssv[4];
        const int tid = threadIdx.x, lane = tid & 63, wid = tid >> 6;
        const float* fb = frp + ((long)b * 64 << 9);
        float s0 = 0.f, s1 = 0.f;
#pragma unroll 8
        for (int k = 0; k < 64; ++k) {
            s0 += fb[(k << 9) + tid];
            s1 += fb[(k << 9) + tid + 256];
        }
        float p = s0 * wvl[tid] + s1 * wvl[tid + 256];
#pragma unroll
        for (int off = 32; off; off >>= 1) p += __shfl_xor(p, off, 64);
        if (lane == 0) ssv[wid] = p;
        __syncthreads();
        const float sv = ssv[0] + ssv[1] + ssv[2] + ssv[3] + 2048.f * wlbv[0];
        const float bl0 = blp[0];
#pragma unroll
        for (int j = 0; j < 8; ++j) {
            int t = tid + j * 256;
            float uu = u[(long)b * TT + t] / rsum[(long)b * TT + t];
            float uf = uu + bl0;
            float vf = sv - uu + bl0;
            float fs  = 1.f / (1.f + __expf(-uf));
            float bsc = 1.f - 1.f / (1.f + __expf(-vf));
            out[(long)BB * CT + (long)b * TT + t] = 0.5f * (fs + bsc);
        }
    }
}

// ---------------------------------------------------------------------------
extern "C" void kernel_launch(void* const* d_in, const int* in_sizes, int n_in,
                              void* d_out, int out_size, void* d_ws, size_t ws_size,
                              hipStream_t stream)
{
    const float* feat = (const float*)d_in[0];
    const float* Wq   = (const float*)d_in[1];
    const float* bq   = (const float*)d_in[2];
    const float* Wk   = (const float*)d_in[3];
    const float* bk   = (const float*)d_in[4];
    const float* Wv   = (const float*)d_in[5];
    const float* bv   = (const float*)d_in[6];
    const float* Ws   = (const float*)d_in[7];
    const float* bs   = (const float*)d_in[8];
    const float* Wl   = (const float*)d_in[9];
    const float* bl   = (const float*)d_in[10];
    float* out = (float*)d_out;

    // workspace layout (bytes)
    if (ws_size < 69316736) return;
    char* ws = (char*)d_ws;
    bf16* featT  = (bf16*)(ws);                  //  8,388,608  [B][T][C]
    bf16* Wbf    = (bf16*)(ws + 8388608);        //  1,572,864  Wq|Wv|Ws bf16
    bf16* Qb     = (bf16*)(ws + 9961472);        //  8,388,608  [B][T][C]  (Q' = Q*wkc)
    bf16* Vn     = (bf16*)(ws + 18350080);       //  8,388,608  [B][T][C]  V natural
    bf16* Vpt    = (bf16*)(ws + 26738688);       //  8,388,608  [B][C][T]  V' = Ws.V^T
    float* vl    = (float*)(ws + 26738688);      //  32,768     [B][T] V·Wl — ALIASES
                                                 //  Vpt head; read by gemm_s BEFORE
                                                 //  gemm_vs overwrites (stream order)
    bf16* S      = (bf16*)(ws + 35127296);       // 33,554,432  [B][T][T] P = exp(s)
    float* wkc   = (float*)(ws + 68689920);      //  2,048
    float* wvl   = (float*)(ws + 68691968);      //  2,048
    float* wlbv  = (float*)(ws + 68694016);      //  64 (8 used)
    float* qb    = (float*)(ws + 68694080);      // 32,768      [B][T] = Q.bk row-dots
    double* stats= (double*)(ws + 68726848);     //  64         [B][2] sum,sumsq
    float* u     = (float*)(ws + 68726912);      // 32,768      [B][T] = P.vl row-dots
    float* rsum  = (float*)(ws + 68759680);      // 32,768      [B][T] = exp row-sums
    float* frp   = (float*)(ws + 68792448);      // 524,288     [B][64][C] feat col-sums

    bf16* Wq_bf = Wbf;
    bf16* Wv_bf = Wbf + 262144;
    bf16* Ws_bf = Wbf + 524288;

    // transpose + weight-cast + small precomputes, one dispatch
    prep_kernel<<<4624, 256, 0, stream>>>(feat, featT, Wq, Wv, Ws, Wbf, Wk, Wl, bv,
                                          wkc, wvl, wlbv, frp, qb, u, rsum, stats, vl);
    // Q' and Vn with shared featT staging (pipelined); V-half accumulates vl
    gemm_qv_kernel<<<dim3(8, 16, 4), 512, 0, stream>>>(
        featT, Wq_bf, Wv_bf, Qb, Vn, bq, bv, wkc, bk, qb, Wl, vl);
    // P = exp(...) + rsum + u_raw atomics (8-phase 256^2); reads vl
    gemm_s256_kernel<<<256, 512, 0, stream>>>(Qb, featT, S, qb, rsum, vl, u);
    // V' = Ws.V^T  (pipelined; overwrites the vl alias — must run after gemm_s)
    gemm_vs_kernel<<<256, 512, 0, stream>>>(Vn, Ws_bf, Vpt);
    // out = feat + (P.V')/rsum + bs + LN stats (pipelined)
    gemm_out_kernel<<<256, 512, 0, stream>>>(S, Vpt, out, bs, feat, rsum, stats);
    ln_score_kernel<<<4100, 256, 0, stream>>>(out, stats, u, frp, wvl, wlbv, bl, rsum);
}